// Round 1
// baseline (525.975 us; speedup 1.0000x reference)
//
#include <hip/hip_runtime.h>

// B=16384, F=40, D=32, fp32 — fully fused single kernel.
// Block = 256 threads = 4 waves, owns NB=8 batch elements; wave w owns
// fields [10w, 10w+10).
//  Stage A: h_out[b,f,d] = sum_e Wout[f,d,e] h[b,f,e]      -> LDS (40 KB)
//  Stage B: aggr[b,f,d]  = sum_g g[b,f,g] h_out[b,g,d]     -> d_out (global)
//  Stage C: out[b,f,d]   = sum_e Win[f,d,e] aggr[b,f,e]+bias, in place
// R3 lesson (this round's theory): thread-per-row field_transform was
// latency-serialized (VGPR 32, VALUBusy 11%) + 2.3x write amplification;
// lane=d mapping keeps W in regs (reused over b), makes h reads broadcast
// (one line fetch per row) and stores fully coalesced. Stage C reads back
// this wave's own aggr rows from L2 (same-wave VMEM RAW, no barrier).

#define B_TOT 16384
#define FF    40
#define DD    32
#define NB    8     // batch elements per block
#define WF    10    // fields per wave (4 waves x 10 = 40)

__global__ __launch_bounds__(256)
void graph_layer_fused(const float* __restrict__ g,
                       const float* __restrict__ h,
                       const float* __restrict__ Win,
                       const float* __restrict__ Wout,
                       const float* __restrict__ bias,
                       float* __restrict__ out)
{
    __shared__ __attribute__((aligned(16))) float s_ho[NB * FF * DD]; // 40 KB

    const int t     = threadIdx.x;
    const int w     = t >> 6;          // wave 0..3
    const int l     = t & 63;
    const int b0    = blockIdx.x * NB;
    const int fbase = w * WF;

    // ---------------- stage A: h_out = Wout[f] @ h[b,f,:]  -> LDS ----------
    {
        const int d    = l & 31;
        const int half = l >> 5;
        #pragma unroll 1
        for (int fi = 0; fi < WF; ++fi) {
            const int f = fbase + fi;
            const float4* wrow = (const float4*)(Wout + (size_t)(f * DD + d) * DD);
            float4 wr[8];
            #pragma unroll
            for (int j = 0; j < 8; ++j) wr[j] = wrow[j];     // 32 regs, reused over b
            #pragma unroll
            for (int bp = 0; bp < NB / 2; ++bp) {
                const int bl = 2 * bp + half;
                const float4* hrow =
                    (const float4*)(h + ((size_t)(b0 + bl) * FF + f) * DD);
                float acc = 0.f;
                #pragma unroll
                for (int j = 0; j < 8; ++j) {                 // broadcast loads
                    float4 hv = hrow[j];
                    acc += wr[j].x * hv.x + wr[j].y * hv.y
                         + wr[j].z * hv.z + wr[j].w * hv.w;
                }
                s_ho[(bl * FF + f) * DD + d] = acc;           // bank d, 2-way: free
            }
        }
    }
    __syncthreads();   // stage B reads h_out across all waves' fields

    // ---------------- stage B: aggr = g[b,f,:] @ h_out[b,:,:] -> global ----
    {
        const int bl = l >> 3;                 // 0..7 batch element
        const int dq = l & 7;                  // 0..7 d-quad
        const float* grow = g + (size_t)(b0 + bl) * (FF * FF) + (size_t)fbase * FF;
        const float* shob = s_ho + bl * (FF * DD) + dq * 4;

        float4 acc[WF];
        #pragma unroll
        for (int fi = 0; fi < WF; ++fi) acc[fi] = make_float4(0.f, 0.f, 0.f, 0.f);

        // g double-buffer: prefetch chunk gc=0
        float4 gv[WF];
        #pragma unroll
        for (int fi = 0; fi < WF; ++fi)
            gv[fi] = *(const float4*)(grow + fi * FF);

        #pragma unroll 1
        for (int gc = 0; gc < 10; ++gc) {
            // dense conflict-free ds_read_b128 (banks dq*4+j cover all 32)
            float4 hv[4];
            #pragma unroll
            for (int i = 0; i < 4; ++i)
                hv[i] = *(const float4*)(shob + (4 * gc + i) * DD);

            float4 gn[WF];
            if (gc < 9) {
                #pragma unroll
                for (int fi = 0; fi < WF; ++fi)
                    gn[fi] = *(const float4*)(grow + fi * FF + 4 * gc + 4);
            }

            #pragma unroll
            for (int fi = 0; fi < WF; ++fi) {
                float4 gf = gv[fi];
                acc[fi].x += gf.x*hv[0].x + gf.y*hv[1].x + gf.z*hv[2].x + gf.w*hv[3].x;
                acc[fi].y += gf.x*hv[0].y + gf.y*hv[1].y + gf.z*hv[2].y + gf.w*hv[3].y;
                acc[fi].z += gf.x*hv[0].z + gf.y*hv[1].z + gf.z*hv[2].z + gf.w*hv[3].z;
                acc[fi].w += gf.x*hv[0].w + gf.y*hv[1].w + gf.z*hv[2].w + gf.w*hv[3].w;
            }
            #pragma unroll
            for (int fi = 0; fi < WF; ++fi) gv[fi] = gn[fi];
        }

        // coalesced: per b, 8 dq-lanes write 128 B contiguous
        #pragma unroll
        for (int fi = 0; fi < WF; ++fi)
            *(float4*)(out + ((size_t)(b0 + bl) * FF + fbase + fi) * DD + dq * 4)
                = acc[fi];
    }

    // Drain this wave's aggr stores to L2 before reading them back (same-wave
    // VMEM RAW; rows are private to this wave, so no barrier needed).
    asm volatile("s_waitcnt vmcnt(0)" ::: "memory");

    // ---------------- stage C: out = Win[f] @ aggr + bias, in place --------
    {
        const int d    = l & 31;
        const int half = l >> 5;
        const float bv = bias[d];
        #pragma unroll 1
        for (int fi = 0; fi < WF; ++fi) {
            const int f = fbase + fi;
            const float4* wrow = (const float4*)(Win + (size_t)(f * DD + d) * DD);
            float4 wr[8];
            #pragma unroll
            for (int j = 0; j < 8; ++j) wr[j] = wrow[j];
            #pragma unroll
            for (int bp = 0; bp < NB / 2; ++bp) {
                const int bl = 2 * bp + half;
                float* arow = out + ((size_t)(b0 + bl) * FF + f) * DD;
                float acc = bv;
                #pragma unroll
                for (int j = 0; j < 8; ++j) {                 // L2-hot broadcast
                    float4 av = ((const float4*)arow)[j];
                    acc += wr[j].x * av.x + wr[j].y * av.y
                         + wr[j].z * av.z + wr[j].w * av.w;
                }
                // all lanes' reads of this row complete before the wave-wide
                // store issues (data dependency) -> in-place safe
                arow[d] = acc;
            }
        }
    }
}

extern "C" void kernel_launch(void* const* d_in, const int* in_sizes, int n_in,
                              void* d_out, int out_size, void* d_ws, size_t ws_size,
                              hipStream_t stream) {
    const float* g    = (const float*)d_in[0];
    const float* h    = (const float*)d_in[1];
    const float* Win  = (const float*)d_in[2];
    const float* Wout = (const float*)d_in[3];
    const float* bias = (const float*)d_in[4];
    float* out = (float*)d_out;

    dim3 block(256);
    dim3 grid(B_TOT / NB);   // 2048 blocks
    graph_layer_fused<<<grid, block, 0, stream>>>(g, h, Win, Wout, bias, out);
}

// Round 2
// 374.361 us; speedup vs baseline: 1.4050x; 1.4050x over previous
//
#include <hip/hip_runtime.h>

// B=16384, F=40, D=32, fp32 — fused single kernel, all intermediates in LDS.
// Block = 256 thr = 4 waves, owns NB=8 batch elements; wave w owns fields
// [10w, 10w+10). One 40 KB LDS buffer reused three times:
//   phase 0: stage h[b][f][d] (coalesced bulk copy)
//   stage A: h_out = Wout[f] @ h   -> regs -> s_buf as [f][b][d]
//   stage B: aggr  = g @ h_out     -> regs -> s_buf as [f][b][d]
//   stage C: out   = Win[f] @ aggr + bias -> global (only global write)
// R1 lesson: global aggr round-trip + single-row-in-flight broadcast loads
// left waves stalled 93% of cycles (VALUBusy 18.7 @ occ 32). Everything
// latency-critical now lives in LDS; g is the only streamed global read in
// the main loop and is rolling-prefetched. [f][b][d] makes stage-B ds_reads
// dense contiguous 1024 B/instr (lane offset l*16B) — conflict-free.

#define B_TOT 16384
#define FF    40
#define DD    32
#define NB    8
#define WF    10

__global__ __launch_bounds__(256, 4)   // cap VGPR <=128 -> 16 waves/CU
void graph_layer_fused(const float* __restrict__ g,
                       const float* __restrict__ h,
                       const float* __restrict__ Win,
                       const float* __restrict__ Wout,
                       const float* __restrict__ bias,
                       float* __restrict__ out)
{
    __shared__ __attribute__((aligned(16))) float s_buf[NB * FF * DD]; // 40 KB

    const int t     = threadIdx.x;
    const int w     = t >> 6;
    const int l     = t & 63;
    const int b0    = blockIdx.x * NB;
    const int fbase = w * WF;

    // ---- phase 0: bulk-stage h for 8 b's, linear [b][f][d] ----------------
    {
        const float4* src = (const float4*)(h + (size_t)b0 * (FF * DD));
        float4* dst = (float4*)s_buf;
        #pragma unroll
        for (int k = 0; k < 10; ++k)
            dst[t + k * 256] = src[t + k * 256];
    }
    __syncthreads();

    // ---- stage A: h_out (regs) = Wout[f] @ h[b,f,:] -----------------------
    const int d    = l & 31;
    const int half = l >> 5;
    float accA[WF][4];                       // [fi][bp] scalars
    #pragma unroll
    for (int fi = 0; fi < WF; ++fi) {
        const int f = fbase + fi;
        const float4* wrow = (const float4*)(Wout + ((size_t)f * DD + d) * DD);
        float4 wr[8];
        #pragma unroll
        for (int j = 0; j < 8; ++j) wr[j] = wrow[j];
        #pragma unroll
        for (int bp = 0; bp < 4; ++bp) {
            const int bl = 2 * bp + half;
            const float4* hrow = (const float4*)(s_buf + (bl * FF + f) * DD);
            float p0 = 0.f, p1 = 0.f, p2 = 0.f, p3 = 0.f;   // depth-8 chains
            #pragma unroll
            for (int j = 0; j < 8; ++j) {
                float4 hv = hrow[j];                          // LDS broadcast
                p0 += wr[j].x * hv.x; p1 += wr[j].y * hv.y;
                p2 += wr[j].z * hv.z; p3 += wr[j].w * hv.w;
            }
            accA[fi][bp] = (p0 + p1) + (p2 + p3);
        }
    }
    __syncthreads();                         // all h reads done
    #pragma unroll
    for (int fi = 0; fi < WF; ++fi)
        #pragma unroll
        for (int bp = 0; bp < 4; ++bp) {
            const int bl = 2 * bp + half;
            s_buf[(fbase + fi) * (NB * DD) + bl * DD + d] = accA[fi][bp];
        }
    __syncthreads();                         // h_out [f][b][d] complete

    // ---- stage B: aggr (regs) = sum_G g[b,f,G] * h_out[G,b,:] -------------
    const int bl = l >> 3;                   // batch element 0..7
    const int dq = l & 7;                    // d-quad 0..7
    const float* grow = g + (size_t)(b0 + bl) * (FF * FF) + (size_t)fbase * FF;
    const float* sb   = s_buf + l * 4;       // lane's 16 B in each G-row

    float4 accB[WF];
    float4 gv[WF];
    #pragma unroll
    for (int fi = 0; fi < WF; ++fi) {
        accB[fi] = make_float4(0.f, 0.f, 0.f, 0.f);
        gv[fi]   = *(const float4*)(grow + fi * FF);          // prefetch gc=0
    }
    #pragma unroll 1
    for (int gc = 0; gc < 10; ++gc) {
        float4 hv[4];
        #pragma unroll
        for (int i = 0; i < 4; ++i)          // dense 1024 B ds_read_b128
            hv[i] = *(const float4*)(sb + (4 * gc + i) * (NB * DD));
        const int gnx = (gc < 9) ? 4 * gc + 4 : 36;   // rolling prefetch addr
        #pragma unroll
        for (int fi = 0; fi < WF; ++fi) {
            float4 gf = gv[fi];
            accB[fi].x += gf.x*hv[0].x + gf.y*hv[1].x + gf.z*hv[2].x + gf.w*hv[3].x;
            accB[fi].y += gf.x*hv[0].y + gf.y*hv[1].y + gf.z*hv[2].y + gf.w*hv[3].y;
            accB[fi].z += gf.x*hv[0].z + gf.y*hv[1].z + gf.z*hv[2].z + gf.w*hv[3].z;
            accB[fi].w += gf.x*hv[0].w + gf.y*hv[1].w + gf.z*hv[2].w + gf.w*hv[3].w;
            gv[fi] = *(const float4*)(grow + fi * FF + gnx);  // overwrite after use
        }
    }
    __syncthreads();                         // all h_out reads done
    #pragma unroll
    for (int fi = 0; fi < WF; ++fi)          // dense 1024 B ds_write_b128
        *(float4*)(s_buf + (fbase + fi) * (NB * DD) + bl * DD + dq * 4) = accB[fi];
    __syncthreads();                         // aggr [f][b][d] complete

    // ---- stage C: out = Win[f] @ aggr + bias (only global write) ----------
    {
        const float bv = bias[d];
        #pragma unroll
        for (int fi = 0; fi < WF; ++fi) {
            const int f = fbase + fi;
            const float4* wrow = (const float4*)(Win + ((size_t)f * DD + d) * DD);
            float4 wr[8];
            #pragma unroll
            for (int j = 0; j < 8; ++j) wr[j] = wrow[j];
            #pragma unroll
            for (int bp = 0; bp < 4; ++bp) {
                const int bl2 = 2 * bp + half;
                const float4* arow = (const float4*)(s_buf + f * (NB * DD) + bl2 * DD);
                float p0 = 0.f, p1 = 0.f, p2 = 0.f, p3 = 0.f;
                #pragma unroll
                for (int j = 0; j < 8; ++j) {
                    float4 av = arow[j];                      // LDS broadcast
                    p0 += wr[j].x * av.x; p1 += wr[j].y * av.y;
                    p2 += wr[j].z * av.z; p3 += wr[j].w * av.w;
                }
                // lanes 0-31 / 32-63 each store one contiguous 128 B row
                out[((size_t)(b0 + bl2) * FF + f) * DD + d] =
                    ((p0 + p1) + (p2 + p3)) + bv;
            }
        }
    }
}

extern "C" void kernel_launch(void* const* d_in, const int* in_sizes, int n_in,
                              void* d_out, int out_size, void* d_ws, size_t ws_size,
                              hipStream_t stream) {
    const float* g    = (const float*)d_in[0];
    const float* h    = (const float*)d_in[1];
    const float* Win  = (const float*)d_in[2];
    const float* Wout = (const float*)d_in[3];
    const float* bias = (const float*)d_in[4];
    float* out = (float*)d_out;

    dim3 block(256);
    dim3 grid(B_TOT / NB);   // 2048 blocks
    graph_layer_fused<<<grid, block, 0, stream>>>(g, h, Win, Wout, bias, out);
}